// Round 9
// baseline (197.755 us; speedup 1.0000x reference)
//
#include <hip/hip_runtime.h>
#include <stdint.h>

typedef __bf16 bf16x8 __attribute__((ext_vector_type(8)));
typedef __bf16 bf16x2 __attribute__((ext_vector_type(2)));
typedef float f32x16 __attribute__((ext_vector_type(16)));
typedef float f32x2 __attribute__((ext_vector_type(2)));

#define CC 64
#define HH 64
#define WW 64
#define OO 128
#define BB 4

// Product table t=0..24: 20 orbit reps (i+j<8) + 5 reflection-fixed (i+j=8).
// NOTE: slot 31 (t=24) is the (4,4) center-square term — it is REAL (R6 bug).
__device__ constexpr int TI[25] = {0,0,0,0,0,0,0,0, 1,1,1,1,1,1, 2,2,2,2, 3,3, 0,1,2,3,4};
__device__ constexpr int TJ[25] = {0,1,2,3,4,5,6,7, 1,2,3,4,5,6, 2,3,4,5, 3,4, 8,7,6,5,4};

// software RNE pack (lo = a, hi = b) — prep only (exact, cost irrelevant there).
__device__ __forceinline__ unsigned int pack_rne(float a, float b) {
  unsigned int ua = __float_as_uint(a);
  ua = ua + 0x7FFFu + ((ua >> 16) & 1u);
  unsigned int ub = __float_as_uint(b);
  ub = ub + 0x7FFFu + ((ub >> 16) & 1u);
  return (ua >> 16) | (ub & 0xFFFF0000u);
}

// 1-instruction pack (lo = a, hi = b) for the hot loop.
__device__ __forceinline__ unsigned int pack_fast(float a, float b) {
#if __has_builtin(__builtin_amdgcn_cvt_pk_bf16_f32)
  bf16x2 r = __builtin_amdgcn_cvt_pk_bf16_f32(a, b);
  return __builtin_bit_cast(unsigned int, r);
#else
  return __builtin_amdgcn_perm(__float_as_uint(b), __float_as_uint(a), 0x07060302u);
#endif
}

// weight value for (n, c, half h, recipe index u in 0..31)  [R3-R8 verified]
__device__ float wval(const float* __restrict__ wl, const float* __restrict__ wv,
                      int n, int c, int h, int u) {
  if (u < 7) {
    if (h == 0) return wl[(n * CC + c) * 9 + u];
    int k = 8 - u;
    return (u < 2) ? wl[(n * CC + c) * 9 + k] : 0.f;
  }
  int tt = u - 7;
  int a = TI[tt], bq = TJ[tt];
  if (h == 0) return wv[((n * CC + c) * 9 + a) * 9 + bq];
  if (tt >= 20) return 0.f;
  int a2 = 8 - bq, b2 = 8 - a;
  return wv[((n * CC + c) * 9 + a2) * 9 + b2];
}

// ---- prep: Wt as uint32[(((c*4+ot)*4+ks)*64 + lane)*4 + epair]  [R3-R8 verified] ----
__global__ void prep_kernel(const float* __restrict__ wl, const float* __restrict__ wv,
                            unsigned int* __restrict__ Wt) {
  int t = blockIdx.x * 256 + threadIdx.x;
  if (t >= CC * 4 * 4 * 64 * 4) return;
  int ep = t & 3;
  int lane = (t >> 2) & 63;
  int ks = (t >> 8) & 3;
  int ot = (t >> 10) & 3;
  int c = t >> 12;
  int n = ot * 32 + (lane & 31);
  int h = lane >> 5;
  int u0 = ks * 8 + ep * 2;
  float v0 = wval(wl, wv, n, c, h, u0);
  float v1 = wval(wl, wv, n, c, h, u0 + 1);
  Wt[t] = pack_rne(v0, v1);
}

// build 32 slots from channel J of the f32x2 group, pack, 4 MFMAs into acc.
template <int J>
__device__ __forceinline__ void build_mfma2(const f32x2 qv[9], const uint4 araw[4],
                                            f32x16& acc) {
  float q[9];
#pragma unroll
  for (int k = 0; k < 9; ++k) q[k] = qv[k][J];
#pragma unroll
  for (int ks = 0; ks < 4; ++ks) {
    float v[8];
#pragma unroll
    for (int e = 0; e < 8; ++e) {
      const int u = ks * 8 + e;
      v[e] = (u < 7) ? q[u] : q[TI[u - 7]] * q[TJ[u - 7]];
    }
    uint4 br;
    br.x = pack_fast(v[0], v[1]);
    br.y = pack_fast(v[2], v[3]);
    br.z = pack_fast(v[4], v[5]);
    br.w = pack_fast(v[6], v[7]);
    acc = __builtin_amdgcn_mfma_f32_32x32x16_bf16(
        __builtin_bit_cast(bf16x8, araw[ks]),
        __builtin_bit_cast(bf16x8, br), acc, 0, 0, 0);
  }
}

// ---- main kernel ----
// grid 256 = (b,y); block 1024 = 16 waves = (ot in 4) x (ch in 4).
// Slab layout transposed to [rs][c] (c-stride 66) so one ds_read_b64 serves
// 2 consecutive channels: 9 b64 per channel-pair per xt (was 18 b32).
__global__ __launch_bounds__(1024, 4) void qconv_kernel(
    const float* __restrict__ img, const unsigned int* __restrict__ Wt,
    const float* __restrict__ bias, float* __restrict__ out) {
  // smem[rs*66 + c]: rs = r*66 + s (r in 0..2, s = x+1 in 0..65), c in 0..63
  // (pad to 66). 13068 floats = 52272 B. Reused as out_s[128][64] in epilogue.
  __shared__ float smem[198 * 66];

  const int t = threadIdx.x;
  const int lane = t & 63;
  const int wq = t >> 6;
  const int ot = wq & 3;
  const int ch = wq >> 2;
  const int n5 = lane & 31;
  const int h = lane >> 5;
  const int b = blockIdx.x >> 6;
  const int y = blockIdx.x & 63;

  // ---- stage image slab (coalesced img reads; LDS writes stride-66 = 2-way free) ----
  {
    const int total = 198 * 64;  // 12672
    for (int idx = t; idx < total; idx += 1024) {
      int c = idx / 198;
      int rs = idx - c * 198;
      int r = rs / 66;
      int s = rs - r * 66;
      int xx = s - 1;
      int yy = y + r - 1;
      float v = 0.f;
      if ((unsigned)xx < 64u && (unsigned)yy < 64u)
        v = img[((b * CC + c) * HH + yy) * WW + xx];
      smem[rs * 66 + c] = v;
    }
  }

  const int c0 = ch * 16;

  // 9 persistent per-lane LDS base pointers (h-reflection baked in):
  // q[k] for channel pair pr, tile xt at qp[k] + pr*2 + xt*2112   (2112 = 32*66)
  const float* qp[9];
#pragma unroll
  for (int k = 0; k < 9; ++k) {
    int r = k / 3, d = k - 3 * r;
    int rr = h ? 2 - r : r;
    int dd = h ? 2 - d : d;
    qp[k] = smem + (rr * 66 + dd + n5) * 66 + c0;
  }
  // A-frag pointer: uint4 index = c*1024 + ot*256 + ks*64 + lane
  const uint4* wb = (const uint4*)Wt + (size_t)c0 * 1024 + ot * 256 + lane;

  __syncthreads();

  f32x16 acc[2];
#pragma unroll
  for (int xt = 0; xt < 2; ++xt)
#pragma unroll
    for (int i = 0; i < 16; ++i) acc[xt][i] = 0.f;

#pragma unroll 1
  for (int pr = 0; pr < 8; ++pr) {  // channel pairs: c = c0 + pr*2 + j
    f32x2 qv0[9], qv1[9];
#pragma unroll
    for (int k = 0; k < 9; ++k) qv0[k] = *(const f32x2*)(qp[k] + pr * 2);
#pragma unroll
    for (int k = 0; k < 9; ++k) qv1[k] = *(const f32x2*)(qp[k] + pr * 2 + 2112);

#pragma unroll
    for (int j = 0; j < 2; ++j) {
      const int crel = pr * 2 + j;
      uint4 araw[4];
#pragma unroll
      for (int ks = 0; ks < 4; ++ks) araw[ks] = wb[crel * 1024 + ks * 64];
      if (j == 0) {
        build_mfma2<0>(qv0, araw, acc[0]);
        build_mfma2<0>(qv1, araw, acc[1]);
      } else {
        build_mfma2<1>(qv0, araw, acc[0]);
        build_mfma2<1>(qv1, araw, acc[1]);
      }
    }
  }

  // ---- epilogue: 4-round cross-ch accumulation into reused LDS ----
  __syncthreads();                 // all waves done reading img slab
  float* out_s = smem;             // [o][x] 128x64 f32
#pragma unroll 1
  for (int rr = 0; rr < 4; ++rr) {
    if (ch == rr) {
#pragma unroll
      for (int xt = 0; xt < 2; ++xt)
#pragma unroll
        for (int r = 0; r < 16; ++r) {
          int o = ot * 32 + (r & 3) + 8 * (r >> 2) + 4 * h;  // 32x32 C/D (m74/m101)
          int x = xt * 32 + n5;
          float v = acc[xt][r];
          if (rr == 0) out_s[o * 64 + x] = v;
          else out_s[o * 64 + x] += v;
        }
    }
    __syncthreads();
  }

  // ---- store: thread t -> o = t/8, 8 consecutive x ----
  {
    int o = t >> 3;
    int x0 = (t & 7) * 8;
    float bo = bias[o];
    float4 v0 = *(const float4*)&out_s[o * 64 + x0];
    float4 v1 = *(const float4*)&out_s[o * 64 + x0 + 4];
    v0.x += bo; v0.y += bo; v0.z += bo; v0.w += bo;
    v1.x += bo; v1.y += bo; v1.z += bo; v1.w += bo;
    float* op = out + ((b * OO + o) * HH + y) * WW + x0;
    *(float4*)op = v0;
    *(float4*)(op + 4) = v1;
  }
}

extern "C" void kernel_launch(void* const* d_in, const int* in_sizes, int n_in,
                              void* d_out, int out_size, void* d_ws, size_t ws_size,
                              hipStream_t stream) {
  const float* image = (const float*)d_in[0];
  const float* wl = (const float*)d_in[1];
  const float* wv = (const float*)d_in[2];
  const float* bias = (const float*)d_in[3];
  float* out = (float*)d_out;
  unsigned int* Wt = (unsigned int*)d_ws;  // 262144 uints = 1 MB

  int prep_elems = CC * 4 * 4 * 64 * 4;    // 262144
  prep_kernel<<<(prep_elems + 255) / 256, 256, 0, stream>>>(wl, wv, Wt);
  qconv_kernel<<<BB * HH, 1024, 0, stream>>>(image, Wt, bias, out);
}

// Round 10
// 97.648 us; speedup vs baseline: 2.0252x; 2.0252x over previous
//
#include <hip/hip_runtime.h>
#include <stdint.h>

typedef __bf16 bf16x8 __attribute__((ext_vector_type(8)));
typedef __bf16 bf16x2 __attribute__((ext_vector_type(2)));
typedef float f32x16 __attribute__((ext_vector_type(16)));

#define CC 64
#define HH 64
#define WW 64
#define OO 128
#define BB 4

// Product table t=0..24: 20 orbit reps (i+j<8) + 5 reflection-fixed (i+j=8).
// NOTE: slot 31 (t=24) is the (4,4) center-square term — it is REAL (R6 bug).
__device__ constexpr int TI[25] = {0,0,0,0,0,0,0,0, 1,1,1,1,1,1, 2,2,2,2, 3,3, 0,1,2,3,4};
__device__ constexpr int TJ[25] = {0,1,2,3,4,5,6,7, 1,2,3,4,5,6, 2,3,4,5, 3,4, 8,7,6,5,4};

// software RNE pack (lo = a, hi = b) — prep only (exact, cost irrelevant there).
__device__ __forceinline__ unsigned int pack_rne(float a, float b) {
  unsigned int ua = __float_as_uint(a);
  ua = ua + 0x7FFFu + ((ua >> 16) & 1u);
  unsigned int ub = __float_as_uint(b);
  ub = ub + 0x7FFFu + ((ub >> 16) & 1u);
  return (ua >> 16) | (ub & 0xFFFF0000u);
}

// 1-instruction pack (lo = a, hi = b) for the hot loop.
__device__ __forceinline__ unsigned int pack_fast(float a, float b) {
#if __has_builtin(__builtin_amdgcn_cvt_pk_bf16_f32)
  bf16x2 r = __builtin_amdgcn_cvt_pk_bf16_f32(a, b);
  return __builtin_bit_cast(unsigned int, r);
#else
  return __builtin_amdgcn_perm(__float_as_uint(b), __float_as_uint(a), 0x07060302u);
#endif
}

// weight value for (n, c, half h, recipe index u in 0..31)  [R3-R8 verified]
__device__ float wval(const float* __restrict__ wl, const float* __restrict__ wv,
                      int n, int c, int h, int u) {
  if (u < 7) {
    if (h == 0) return wl[(n * CC + c) * 9 + u];
    int k = 8 - u;
    return (u < 2) ? wl[(n * CC + c) * 9 + k] : 0.f;
  }
  int tt = u - 7;
  int a = TI[tt], bq = TJ[tt];
  if (h == 0) return wv[((n * CC + c) * 9 + a) * 9 + bq];
  if (tt >= 20) return 0.f;
  int a2 = 8 - bq, b2 = 8 - a;
  return wv[((n * CC + c) * 9 + a2) * 9 + b2];
}

// ---- prep: Wt as uint32[(((c*4+ot)*4+ks)*64 + lane)*4 + epair]  [R3-R8 verified] ----
__global__ void prep_kernel(const float* __restrict__ wl, const float* __restrict__ wv,
                            unsigned int* __restrict__ Wt) {
  int t = blockIdx.x * 256 + threadIdx.x;
  if (t >= CC * 4 * 4 * 64 * 4) return;
  int ep = t & 3;
  int lane = (t >> 2) & 63;
  int ks = (t >> 8) & 3;
  int ot = (t >> 10) & 3;
  int c = t >> 12;
  int n = ot * 32 + (lane & 31);
  int h = lane >> 5;
  int u0 = ks * 8 + ep * 2;
  float v0 = wval(wl, wv, n, c, h, u0);
  float v1 = wval(wl, wv, n, c, h, u0 + 1);
  Wt[t] = pack_rne(v0, v1);
}

// ---- main kernel ----
// grid 256 = (b,y); block 1024 = 16 waves = (ot in 4) x (ch in 4).
// amdgpu_waves_per_eu(4,4): pin occupancy target to 4 waves/EU so the
// allocator uses the full 128-VGPR budget (R5-R9 it squeezed to 56-64 VGPR
// targeting 8/EU that never materializes -> ~3x VALU rematerialization bloat).
__global__ __attribute__((amdgpu_waves_per_eu(4, 4))) __launch_bounds__(1024)
void qconv_kernel(
    const float* __restrict__ img, const unsigned int* __restrict__ Wt,
    const float* __restrict__ bias, float* __restrict__ out) {
  // img slab [c][r][s], s = x+1 (66 wide, zero guards): 50688 B.
  // Reused as out_s[128][64] f32 accumulator (32 KB) in the epilogue.
  __shared__ float smem[CC * 3 * 66];

  const int t = threadIdx.x;
  const int lane = t & 63;
  const int wq = t >> 6;
  const int ot = wq & 3;
  const int ch = wq >> 2;
  const int n5 = lane & 31;
  const int h = lane >> 5;
  const int b = blockIdx.x >> 6;
  const int y = blockIdx.x & 63;

  // ---- stage image slab once (zero-padded; handles all OOB) ----
  {
    const int total = CC * 3 * 66;  // 12672
    for (int idx = t; idx < total; idx += 1024) {
      int c = idx / 198;
      int w = idx - c * 198;
      int r = w / 66;
      int s = w - r * 66;
      int xx = s - 1;
      int yy = y + r - 1;
      float v = 0.f;
      if ((unsigned)xx < 64u && (unsigned)yy < 64u)
        v = img[((b * CC + c) * HH + yy) * WW + xx];
      smem[idx] = v;
    }
  }

  const int c0 = ch * 16;

  // 9 persistent per-lane LDS base pointers, h-reflection baked in.
  const float* qp[9];
#pragma unroll
  for (int k = 0; k < 9; ++k) {
    int r = k / 3, d = k - 3 * r;
    int rr = h ? 2 - r : r;
    int dd = h ? 2 - d : d;
    qp[k] = smem + c0 * 198 + rr * 66 + dd + n5;
  }
  // A-frag pointer: uint4 index = c*1024 + ot*256 + ks*64 + lane
  const uint4* wb = (const uint4*)Wt + (size_t)c0 * 1024 + ot * 256 + lane;

  __syncthreads();

  f32x16 acc[2];
#pragma unroll
  for (int xt = 0; xt < 2; ++xt)
#pragma unroll
    for (int i = 0; i < 16; ++i) acc[xt][i] = 0.f;

#pragma unroll 1
  for (int cg = 0; cg < 4; ++cg) {
#pragma unroll
    for (int i = 0; i < 4; ++i) {
      // A-frags for this channel (L2-resident, unique per wave)
      uint4 araw[4];
#pragma unroll
      for (int ks = 0; ks < 4; ++ks) araw[ks] = wb[i * 1024 + ks * 64];

#pragma unroll
      for (int xt = 0; xt < 2; ++xt) {
        // 9 LDS reads, all immediate offsets off persistent base regs
        float q[9];
#pragma unroll
        for (int k = 0; k < 9; ++k) q[k] = qp[k][i * 198 + xt * 32];
        // 32 slot values: 7 linear + 25 products (slot 31 = q4*q4, REAL)
        float vals[32];
#pragma unroll
        for (int u = 0; u < 7; ++u) vals[u] = q[u];
#pragma unroll
        for (int p = 0; p < 25; ++p) vals[7 + p] = q[TI[p]] * q[TJ[p]];
#pragma unroll
        for (int ks = 0; ks < 4; ++ks) {
          uint4 br;
          br.x = pack_fast(vals[ks * 8 + 0], vals[ks * 8 + 1]);
          br.y = pack_fast(vals[ks * 8 + 2], vals[ks * 8 + 3]);
          br.z = pack_fast(vals[ks * 8 + 4], vals[ks * 8 + 5]);
          br.w = pack_fast(vals[ks * 8 + 6], vals[ks * 8 + 7]);
          acc[xt] = __builtin_amdgcn_mfma_f32_32x32x16_bf16(
              __builtin_bit_cast(bf16x8, araw[ks]),
              __builtin_bit_cast(bf16x8, br), acc[xt], 0, 0, 0);
        }
      }
    }
    // advance bases by 4 channels
#pragma unroll
    for (int k = 0; k < 9; ++k) qp[k] += 4 * 198;
    wb += 4 * 1024;
  }

  // ---- epilogue: 4-round cross-ch accumulation into reused LDS ----
  __syncthreads();                 // all waves done reading img slab
  float* out_s = smem;             // [o][x] 128x64 f32
#pragma unroll 1
  for (int rr = 0; rr < 4; ++rr) {
    if (ch == rr) {
#pragma unroll
      for (int xt = 0; xt < 2; ++xt)
#pragma unroll
        for (int r = 0; r < 16; ++r) {
          int o = ot * 32 + (r & 3) + 8 * (r >> 2) + 4 * h;  // 32x32 C/D (m74/m101)
          int x = xt * 32 + n5;
          float v = acc[xt][r];
          if (rr == 0) out_s[o * 64 + x] = v;
          else out_s[o * 64 + x] += v;
        }
    }
    __syncthreads();
  }

  // ---- store: thread t -> o = t/8, 8 consecutive x ----
  {
    int o = t >> 3;
    int x0 = (t & 7) * 8;
    float bo = bias[o];
    float4 v0 = *(const float4*)&out_s[o * 64 + x0];
    float4 v1 = *(const float4*)&out_s[o * 64 + x0 + 4];
    v0.x += bo; v0.y += bo; v0.z += bo; v0.w += bo;
    v1.x += bo; v1.y += bo; v1.z += bo; v1.w += bo;
    float* op = out + ((b * OO + o) * HH + y) * WW + x0;
    *(float4*)op = v0;
    *(float4*)(op + 4) = v1;
  }
}

extern "C" void kernel_launch(void* const* d_in, const int* in_sizes, int n_in,
                              void* d_out, int out_size, void* d_ws, size_t ws_size,
                              hipStream_t stream) {
  const float* image = (const float*)d_in[0];
  const float* wl = (const float*)d_in[1];
  const float* wv = (const float*)d_in[2];
  const float* bias = (const float*)d_in[3];
  float* out = (float*)d_out;
  unsigned int* Wt = (unsigned int*)d_ws;  // 262144 uints = 1 MB

  int prep_elems = CC * 4 * 4 * 64 * 4;    // 262144
  prep_kernel<<<(prep_elems + 255) / 256, 256, 0, stream>>>(wl, wv, Wt);
  qconv_kernel<<<BB * HH, 1024, 0, stream>>>(image, Wt, bias, out);
}